// Round 5
// baseline (187760.815 us; speedup 1.0000x reference)
//
#include <hip/hip_runtime.h>
#include <math.h>

#define B_ 64
#define T_ 600
#define U_ 64
#define V_ 80
#define H_ 512
#define KA_ 10
#define KO_ 20

// padded weight row strides (floats)
#define S0_ 600
#define S12_ 1108

__device__ __forceinline__ float sigmf(float x){ return 1.0f/(1.0f+expf(-x)); }

__device__ __forceinline__ void spin_ge(int* p, int target){
    while (__hip_atomic_load(p, __ATOMIC_ACQUIRE, __HIP_MEMORY_SCOPE_AGENT) < target){
        __builtin_amdgcn_s_sleep(2);
    }
}

__device__ __forceinline__ void flag_add(int* p){
    __hip_atomic_fetch_add(p, 1, __ATOMIC_RELEASE, __HIP_MEMORY_SCOPE_AGENT);
}

// block-wide wait: lane 0 spins (agent-scope acquire invalidates L1/L2),
// barrier orders everyone else's loads after it. cond must be block-uniform.
#define BLOCK_WAIT(p, tgt) do { if (threadIdx.x == 0) spin_ge((p), (tgt)); __syncthreads(); } while (0)

// ---------------------------------------------------------------------------
// Weight repack: row r -> padded 16B-aligned row:
// [0..2]=stroke w, [3]=pad, [4..83]=attn w, [84..595]=xprev/Whh w, (+[596..1107]=Whh for L1/2)
__global__ __launch_bounds__(64) void k_prep(
    const float* __restrict__ W0ih, const float* __restrict__ W0hh,
    const float* __restrict__ W1ih, const float* __restrict__ W1hh,
    const float* __restrict__ W2ih, const float* __restrict__ W2hh,
    float* __restrict__ wpad)
{
    int r = blockIdx.x;       // 0..6143
    int tid = threadIdx.x;
    if (r < 2048){
        float* dst = wpad + (size_t)r*S0_;
        const float* sih = W0ih + (size_t)r*83;
        const float* shh = W0hh + (size_t)r*512;
        if (tid < 3) dst[tid] = sih[tid];
        if (tid == 3) dst[3] = 0.f;
        for (int v=tid; v<V_; v+=64) dst[4+v] = sih[3+v];
        for (int k=tid; k<H_; k+=64) dst[84+k] = shh[k];
    } else {
        int rr = r - 2048;
        int layer = rr >> 11;     // 0 -> L1, 1 -> L2
        int row = rr & 2047;
        const float* sih = (layer==0 ? W1ih : W2ih) + (size_t)row*595;
        const float* shh = (layer==0 ? W1hh : W2hh) + (size_t)row*512;
        float* dst = wpad + (size_t)2048*S0_ + ((size_t)layer*2048 + row)*S12_;
        if (tid < 3) dst[tid] = sih[tid];
        if (tid == 3) dst[3] = 0.f;
        for (int v=tid; v<V_; v+=64) dst[4+v] = sih[3+v];
        for (int k=tid; k<H_; k+=64) dst[84+k] = sih[83+k];
        for (int k=tid; k<H_; k+=64) dst[596+k] = shh[k];
    }
}

// ---------------------------------------------------------------------------
// Persistent pipelined kernel with flag-based producer/consumer sync.
// Grid 448 x 256:
//   bid [0,128)   : layer0, 4 units each
//   bid [128,256) : layer1, 4 units each
//   bid [256,384) : layer2, 4 units each
//   bid [384,448) : window for batch b = bid-384
// Activations: out_l[t][k>>2][b][k&3]; attn DEPTH-8 RING [t&7][v>>2][b][v&3].
// Back-pressure: window(t) waits c1[t-8],c2[t-8] before overwriting slot t&7.
__global__ __launch_bounds__(256, 2) void k_pipe(
    const float* __restrict__ strokes,
    const int*   __restrict__ char_seq,
    const float* __restrict__ char_mask,
    const float* __restrict__ wpad,
    const float* __restrict__ winW, const float* __restrict__ winb,
    const float* __restrict__ b0, const float* __restrict__ b1, const float* __restrict__ b2,
    float* __restrict__ out0, float* __restrict__ out1, float* __restrict__ out2,
    float* __restrict__ attn, int* __restrict__ sync)
{
    int* c0 = sync;
    int* c1 = sync + 640;
    int* c2 = sync + 1280;
    int* cw = sync + 1920;

    const int bid = blockIdx.x;
    const int tid = threadIdx.x;
    const int b   = tid & 63;
    const int g   = tid >> 6;

    __shared__ float part[4][4][64];
    __shared__ float pp[30][8];
    __shared__ float sa[KA_], sbv[KA_], sk[KA_], skst[KA_];
    __shared__ float sphi[U_];
    __shared__ int   sseq[U_];
    __shared__ float smask[U_];

    if (bid >= 384){
        // ---------------- window role ----------------
        const int wb = bid - 384;
        if (tid < U_){ sseq[tid] = char_seq[wb*U_+tid]; smask[tid] = char_mask[wb*U_+tid]; }
        __syncthreads();
        for (int t=0; t<T_; ++t){
            BLOCK_WAIT(&c0[t], 128);
            // back-pressure: don't overwrite ring slot t&7 (=attn[t-8]) until
            // layers 1/2 have consumed step t-8.
            if (t >= 8){
                BLOCK_WAIT(&c1[t-8], 128);
                BLOCK_WAIT(&c2[t-8], 128);
            }
            if (tid < 240){
                int r = tid >> 3, p8 = tid & 7;
                const float4* hp = (const float4*)(out0 + (size_t)t*32768);
                const float4* wr = (const float4*)(winW + (size_t)r*H_);
                float acc = 0.f;
                int kq0 = p8*16;
                #pragma unroll 4
                for (int i=0; i<16; ++i){
                    float4 xv = hp[(size_t)(kq0+i)*64 + wb];
                    float4 wv = wr[kq0+i];
                    acc += xv.x*wv.x + xv.y*wv.y + xv.z*wv.z + xv.w*wv.w;
                }
                pp[r][p8] = acc;
            }
            __syncthreads();
            if (tid < 30){
                float p = winb[tid];
                #pragma unroll
                for (int i=0; i<8; ++i) p += pp[tid][i];
                float e = expf(p);
                if (tid < KA_) sa[tid] = e;
                else if (tid < 2*KA_) sbv[tid-KA_] = e;
                else {
                    int a2 = tid - 2*KA_;
                    float kn = ((t == 0) ? 0.f : skst[a2]) + e;
                    skst[a2] = kn; sk[a2] = kn;
                }
            }
            __syncthreads();
            if (tid < U_){
                float acc = 0.f;
                #pragma unroll
                for (int a=0; a<KA_; ++a){
                    float d = sk[a] - (float)tid;
                    acc += sa[a]*expf(-sbv[a]*d*d);
                }
                sphi[tid] = acc * smask[tid]*smask[tid];
            }
            __syncthreads();
            if (tid < V_){
                float wv = 0.f;
                for (int u=0; u<U_; ++u) wv += (sseq[u] == tid) ? sphi[u] : 0.f;
                attn[(size_t)(t&7)*5120 + (size_t)(tid>>2)*256 + wb*4 + (tid&3)] = wv;
            }
            __syncthreads();
            if (tid == 0) flag_add(&cw[t]);
        }
        return;
    }

    // ---------------- layer role ----------------
    const int l  = bid >> 7;          // 0,1,2
    const int ub = (bid & 127) * 4;

    const float* wbase; const float* bias_p; const float* xprev; float* outp;
    int* cself; int* cprev; size_t wstride; int roff;
    if (l == 0){ wbase = wpad;                                          wstride = S0_;  bias_p = b0; outp = out0; xprev = nullptr; cself = c0; cprev = nullptr; roff = 84; }
    else if (l == 1){ wbase = wpad + (size_t)2048*S0_;                  wstride = S12_; bias_p = b1; outp = out1; xprev = out0;   cself = c1; cprev = c0;     roff = 596; }
    else { wbase = wpad + (size_t)2048*S0_ + (size_t)2048*S12_;         wstride = S12_; bias_p = b2; outp = out2; xprev = out1;   cself = c2; cprev = c1;     roff = 596; }

    const float* wr = wbase + ((size_t)g*H_ + ub)*wstride;
    const float* wr1 = wr + wstride;
    const float* wr2 = wr + 2*wstride;
    const float* wr3 = wr + 3*wstride;

    // combine thread (g,b) owns unit u = ub+g
    const int cu = ub + g;
    const float bgi = bias_p[0*H_+cu];
    const float bgf = bias_p[1*H_+cu];
    const float bgg = bias_p[2*H_+cu];
    const float bgo = bias_p[3*H_+cu];
    float creg = 0.f;

    for (int t=0; t<T_; ++t){
        float a0, a1, a2, a3;
        // stroke part (no dependency)
        {
            const float* sr = strokes + ((size_t)b*T_ + t)*3;
            float sx=sr[0], sy=sr[1], sz=sr[2];
            a0 = sx*wr[0]  + sy*wr[1]  + sz*wr[2];
            a1 = sx*wr1[0] + sy*wr1[1] + sz*wr1[2];
            a2 = sx*wr2[0] + sy*wr2[1] + sz*wr2[2];
            a3 = sx*wr3[0] + sy*wr3[1] + sz*wr3[2];
        }
        // own recurrence: needs own layer's h(t-1)
        if (t > 0){
            BLOCK_WAIT(&cself[t-1], 128);
            const float4* hp = (const float4*)(outp + (size_t)(t-1)*32768) + b;
            #pragma unroll 4
            for (int kq=0; kq<128; ++kq){
                float4 xv = hp[kq*64];
                float4 q0 = *(const float4*)(wr  + roff + kq*4);
                float4 q1 = *(const float4*)(wr1 + roff + kq*4);
                float4 q2 = *(const float4*)(wr2 + roff + kq*4);
                float4 q3 = *(const float4*)(wr3 + roff + kq*4);
                a0 += xv.x*q0.x + xv.y*q0.y + xv.z*q0.z + xv.w*q0.w;
                a1 += xv.x*q1.x + xv.y*q1.y + xv.z*q1.z + xv.w*q1.w;
                a2 += xv.x*q2.x + xv.y*q2.y + xv.z*q2.z + xv.w*q2.w;
                a3 += xv.x*q3.x + xv.y*q3.y + xv.z*q3.z + xv.w*q3.w;
            }
        }
        // previous-layer h part (layers 1/2)
        if (l > 0){
            BLOCK_WAIT(&cprev[t], 128);
            const float4* hp = (const float4*)(xprev + (size_t)t*32768) + b;
            #pragma unroll 4
            for (int kq=0; kq<128; ++kq){
                float4 xv = hp[kq*64];
                float4 q0 = *(const float4*)(wr  + 84 + kq*4);
                float4 q1 = *(const float4*)(wr1 + 84 + kq*4);
                float4 q2 = *(const float4*)(wr2 + 84 + kq*4);
                float4 q3 = *(const float4*)(wr3 + 84 + kq*4);
                a0 += xv.x*q0.x + xv.y*q0.y + xv.z*q0.z + xv.w*q0.w;
                a1 += xv.x*q1.x + xv.y*q1.y + xv.z*q1.z + xv.w*q1.w;
                a2 += xv.x*q2.x + xv.y*q2.y + xv.z*q2.z + xv.w*q2.w;
                a3 += xv.x*q3.x + xv.y*q3.y + xv.z*q3.z + xv.w*q3.w;
            }
        }
        // attention part (layer0 uses attn[t-1], layers1/2 attn[t])
        {
            int ta = (l == 0) ? (t-1) : t;
            if (ta >= 0){
                BLOCK_WAIT(&cw[ta], 64);
                const float4* ap = (const float4*)(attn + (size_t)(ta&7)*5120) + b;
                #pragma unroll 4
                for (int vq=0; vq<20; ++vq){
                    float4 xv = ap[vq*64];
                    float4 q0 = *(const float4*)(wr  + 4 + vq*4);
                    float4 q1 = *(const float4*)(wr1 + 4 + vq*4);
                    float4 q2 = *(const float4*)(wr2 + 4 + vq*4);
                    float4 q3 = *(const float4*)(wr3 + 4 + vq*4);
                    a0 += xv.x*q0.x + xv.y*q0.y + xv.z*q0.z + xv.w*q0.w;
                    a1 += xv.x*q1.x + xv.y*q1.y + xv.z*q1.z + xv.w*q1.w;
                    a2 += xv.x*q2.x + xv.y*q2.y + xv.z*q2.z + xv.w*q2.w;
                    a3 += xv.x*q3.x + xv.y*q3.y + xv.z*q3.z + xv.w*q3.w;
                }
            }
        }
        part[g][0][b] = a0;
        part[g][1][b] = a1;
        part[g][2][b] = a2;
        part[g][3][b] = a3;
        __syncthreads();
        {
            // combine: thread (g,b) finishes unit cu = ub+g
            float gi  = part[0][g][b] + bgi;
            float gf  = part[1][g][b] + bgf;
            float gg_ = part[2][g][b] + bgg;
            float go  = part[3][g][b] + bgo;
            float cold = (t == 0) ? 0.f : creg;
            float cnew = sigmf(gf)*cold + sigmf(gi)*tanhf(gg_);
            creg = cnew;
            float h = sigmf(go)*tanhf(cnew);
            outp[(size_t)t*32768 + (size_t)(cu>>2)*256 + b*4 + (cu&3)] = h;
        }
        __syncthreads();
        if (tid == 0) flag_add(&cself[t]);
    }
}

// ---------------------------------------------------------------------------
// FC head + output transforms, fused. One block per t.
__global__ __launch_bounds__(256) void k_fc(
    const float* __restrict__ out0, const float* __restrict__ out1, const float* __restrict__ out2,
    const float* __restrict__ fcW, const float* __restrict__ fcb, float* __restrict__ out)
{
    int t = blockIdx.x; int tid = threadIdx.x;
    int b = tid & 63; int gq = tid >> 6;
    __shared__ float smraw[128*65];   // union: acts[128][65] / fin[121][64]

    float acc[31];
    #pragma unroll
    for (int i=0; i<31; ++i) acc[i] = 0.f;

    const float* outs[3] = {out0, out1, out2};
    for (int seg=0; seg<3; ++seg){
        const float* o = outs[seg] + (size_t)t*32768;
        for (int kc=0; kc<H_; kc+=128){
            __syncthreads();
            #pragma unroll
            for (int r=0; r<8; ++r){
                int idx = tid + 256*r;          // 0..2047
                int kql = idx >> 6;             // 0..31
                int bb  = idx & 63;
                float4 v = *(const float4*)(o + (size_t)((kc>>2) + kql)*256 + bb*4);
                smraw[(4*kql+0)*65+bb] = v.x;
                smraw[(4*kql+1)*65+bb] = v.y;
                smraw[(4*kql+2)*65+bb] = v.z;
                smraw[(4*kql+3)*65+bb] = v.w;
            }
            __syncthreads();
            for (int kk=0; kk<128; kk+=4){
                float a0 = smraw[(kk+0)*65+b];
                float a1 = smraw[(kk+1)*65+b];
                float a2 = smraw[(kk+2)*65+b];
                float a3 = smraw[(kk+3)*65+b];
                int K = seg*H_ + kc + kk;
                #pragma unroll
                for (int i=0; i<30; ++i){
                    float4 w = *(const float4*)(fcW + (size_t)(gq+4*i)*1536 + K);
                    acc[i] += a0*w.x + a1*w.y + a2*w.z + a3*w.w;
                }
                if (gq == 0){
                    float4 w = *(const float4*)(fcW + (size_t)120*1536 + K);
                    acc[30] += a0*w.x + a1*w.y + a2*w.z + a3*w.w;
                }
            }
        }
    }
    __syncthreads();
    #pragma unroll
    for (int i=0; i<30; ++i) smraw[(gq+4*i)*64 + b] = acc[i] + fcb[gq+4*i];
    if (gq == 0) smraw[120*64 + b] = acc[30] + fcb[120];
    __syncthreads();

    if (tid < 64){
        size_t bt = (size_t)b*T_ + t;
        float* myu = out + 768000;
        #pragma unroll
        for (int q=0; q<10; ++q){
            float4 v;
            v.x = smraw[(4*q+0)*64+b]; v.y = smraw[(4*q+1)*64+b];
            v.z = smraw[(4*q+2)*64+b]; v.w = smraw[(4*q+3)*64+b];
            *(float4*)(myu + bt*40 + 4*q) = v;
        }
        float* lsg = out + 2304000;
        #pragma unroll
        for (int q=0; q<10; ++q){
            float4 v;
            v.x = smraw[(40+4*q+0)*64+b]; v.y = smraw[(40+4*q+1)*64+b];
            v.z = smraw[(40+4*q+2)*64+b]; v.w = smraw[(40+4*q+3)*64+b];
            *(float4*)(lsg + bt*40 + 4*q) = v;
        }
        float pi[KO_];
        float m = -1e30f;
        #pragma unroll
        for (int ko=0; ko<KO_; ++ko){ pi[ko] = smraw[(80+ko)*64+b]; m = fmaxf(m, pi[ko]); }
        float s = 0.f;
        #pragma unroll
        for (int ko=0; ko<KO_; ++ko) s += expf(pi[ko]-m);
        float lse = m + logf(s);
        #pragma unroll
        for (int q=0; q<5; ++q){
            float4 v;
            v.x = pi[4*q+0]-lse; v.y = pi[4*q+1]-lse; v.z = pi[4*q+2]-lse; v.w = pi[4*q+3]-lse;
            *(float4*)(out + bt*20 + 4*q) = v;
        }
        float* rho = out + 3840000;
        #pragma unroll
        for (int q=0; q<5; ++q){
            float4 v;
            v.x = tanhf(smraw[(100+4*q+0)*64+b]); v.y = tanhf(smraw[(100+4*q+1)*64+b]);
            v.z = tanhf(smraw[(100+4*q+2)*64+b]); v.w = tanhf(smraw[(100+4*q+3)*64+b]);
            *(float4*)(rho + bt*20 + 4*q) = v;
        }
        out[4608000 + bt] = 1.f/(1.f + expf(smraw[120*64+b]));
    }
}

// ---------------------------------------------------------------------------
extern "C" void kernel_launch(void* const* d_in, const int* in_sizes, int n_in,
                              void* d_out, int out_size, void* d_ws, size_t ws_size,
                              hipStream_t stream)
{
    const int*   char_seq  = (const int*)  d_in[0];
    const float* char_mask = (const float*)d_in[1];
    const float* strokes   = (const float*)d_in[2];
    const float* W0ih = (const float*)d_in[4];
    const float* W0hh = (const float*)d_in[5];
    const float* b0   = (const float*)d_in[6];
    const float* winW = (const float*)d_in[7];
    const float* winb = (const float*)d_in[8];
    const float* W1ih = (const float*)d_in[9];
    const float* W1hh = (const float*)d_in[10];
    const float* b1   = (const float*)d_in[11];
    const float* W2ih = (const float*)d_in[12];
    const float* W2hh = (const float*)d_in[13];
    const float* b2   = (const float*)d_in[14];
    const float* fcW  = (const float*)d_in[15];
    const float* fcb  = (const float*)d_in[16];

    float* ws   = (float*)d_ws;
    float* out0 = ws;                       // [600][128][64][4] = 19,660,800
    float* out1 = out0 + 19660800;
    float* out2 = out1 + 19660800;
    float* attn = out2 + 19660800;          // RING [8][20][64][4] = 40,960
    float* wpad = attn + 40960;             // 5,767,168
    int*   sync = (int*)(wpad + 5767168);   // 2,560 ints (c0,c1,c2,cw @ 640 each)

    hipMemsetAsync(sync, 0, 2560*sizeof(int), stream);

    hipLaunchKernelGGL(k_prep, dim3(6144), dim3(64), 0, stream,
        W0ih, W0hh, W1ih, W1hh, W2ih, W2hh, wpad);

    hipLaunchKernelGGL(k_pipe, dim3(448), dim3(256), 0, stream,
        strokes, char_seq, char_mask, wpad, winW, winb, b0, b1, b2,
        out0, out1, out2, attn, sync);

    hipLaunchKernelGGL(k_fc, dim3(600), dim3(256), 0, stream,
        out0, out1, out2, fcW, fcb, (float*)d_out);
}

// Round 6
// 53083.636 us; speedup vs baseline: 3.5371x; 3.5371x over previous
//
#include <hip/hip_runtime.h>
#include <math.h>

#define B_ 64
#define T_ 600
#define U_ 64
#define V_ 80
#define H_ 512
#define KA_ 10
#define KO_ 20

// padded weight row strides (floats)
#define S0_ 600
#define S12_ 1108

__device__ __forceinline__ float sigmf(float x){ return 1.0f/(1.0f+expf(-x)); }

// --- coherent (cache-bypassing / write-through) primitives: NO buffer_inv, NO wbl2 ---
__device__ __forceinline__ int coh_load_i32(const int* p){
    int v;
    asm volatile("global_load_dword %0, %1, off sc0 sc1\n\ts_waitcnt vmcnt(0)"
                 : "=v"(v) : "v"(p) : "memory");
    return v;
}
__device__ __forceinline__ void coh_store_f32(float* p, float v){
    asm volatile("global_store_dword %0, %1, off sc0 sc1" :: "v"(p), "v"(v) : "memory");
}
__device__ __forceinline__ void coh_store_u32(unsigned* p, unsigned v){
    asm volatile("global_store_dword %0, %1, off sc0 sc1" :: "v"(p), "v"(v) : "memory");
}
__device__ __forceinline__ void spin_ge(int* p, int target){
    while (coh_load_i32(p) < target) __builtin_amdgcn_s_sleep(4);
}
// block-wide wait: lane 0 spins (bypassing loads, no cache maintenance),
// s_barrier orders everyone's subsequent loads. cond must be block-uniform.
#define BLOCK_WAIT(p, tgt) do { if (threadIdx.x == 0) spin_ge((p), (tgt)); __syncthreads(); } while (0)

__device__ __forceinline__ float blo(unsigned u){ return __uint_as_float(u << 16); }
__device__ __forceinline__ float bhi(unsigned u){ return __uint_as_float(u & 0xffff0000u); }
__device__ __forceinline__ unsigned pack_bf16(float a, float b){
    return ((__float_as_uint(a) + 0x8000u) >> 16) | ((__float_as_uint(b) + 0x8000u) & 0xffff0000u);
}

// ---------------------------------------------------------------------------
// Weight repack: row r -> padded 16B-aligned row:
// [0..2]=stroke w, [3]=pad, [4..83]=attn w, [84..595]=xprev/Whh w, (+[596..1107]=Whh for L1/2)
__global__ __launch_bounds__(64) void k_prep(
    const float* __restrict__ W0ih, const float* __restrict__ W0hh,
    const float* __restrict__ W1ih, const float* __restrict__ W1hh,
    const float* __restrict__ W2ih, const float* __restrict__ W2hh,
    float* __restrict__ wpad)
{
    int r = blockIdx.x;       // 0..6143
    int tid = threadIdx.x;
    if (r < 2048){
        float* dst = wpad + (size_t)r*S0_;
        const float* sih = W0ih + (size_t)r*83;
        const float* shh = W0hh + (size_t)r*512;
        if (tid < 3) dst[tid] = sih[tid];
        if (tid == 3) dst[3] = 0.f;
        for (int v=tid; v<V_; v+=64) dst[4+v] = sih[3+v];
        for (int k=tid; k<H_; k+=64) dst[84+k] = shh[k];
    } else {
        int rr = r - 2048;
        int layer = rr >> 11;     // 0 -> L1, 1 -> L2
        int row = rr & 2047;
        const float* sih = (layer==0 ? W1ih : W2ih) + (size_t)row*595;
        const float* shh = (layer==0 ? W1hh : W2hh) + (size_t)row*512;
        float* dst = wpad + (size_t)2048*S0_ + ((size_t)layer*2048 + row)*S12_;
        if (tid < 3) dst[tid] = sih[tid];
        if (tid == 3) dst[3] = 0.f;
        for (int v=tid; v<V_; v+=64) dst[4+v] = sih[3+v];
        for (int k=tid; k<H_; k+=64) dst[84+k] = sih[83+k];
        for (int k=tid; k<H_; k+=64) dst[596+k] = shh[k];
    }
}

// ---------------------------------------------------------------------------
// Persistent pipelined kernel, flag-synced, zero cache-maintenance in steady state.
// Grid 448 x 256:
//   bid [0,128)   : layer0, 4 units each
//   bid [128,256) : layer1, 4 units each
//   bid [256,384) : layer2, 4 units each
//   bid [384,448) : window for batch b = bid-384
// h: out_l[t][k>>2][b][k&3] fp32 FULL history (fresh addresses each step).
// attn: bf16 pairs, FULL history attnb[t][b][40] (cell c = chars 2c,2c+1).
// Producers: sc0/sc1 write-through stores -> __syncthreads (vmcnt drain) -> atomicAdd flag.
// Consumers: bypassing poll -> barrier -> normal cached loads (fresh addresses).
__global__ __launch_bounds__(256, 2) void k_pipe(
    const float* __restrict__ strokes,
    const int*   __restrict__ char_seq,
    const float* __restrict__ char_mask,
    const float* __restrict__ wpad,
    const float* __restrict__ winW, const float* __restrict__ winb,
    const float* __restrict__ b0, const float* __restrict__ b1, const float* __restrict__ b2,
    float* __restrict__ out0, float* __restrict__ out1, float* __restrict__ out2,
    unsigned* __restrict__ attnb, int* __restrict__ sync)
{
    // Per-call clean slate: kill stale L2 lines (poison / previous replay).
    // This is the ONLY cache invalidation in the whole kernel.
    __builtin_amdgcn_fence(__ATOMIC_ACQUIRE, "agent");

    int* c0 = sync;
    int* c1 = sync + 640;
    int* c2 = sync + 1280;
    int* cw = sync + 1920;

    const int bid = blockIdx.x;
    const int tid = threadIdx.x;
    const int b   = tid & 63;
    const int g   = tid >> 6;

    __shared__ float part[4][4][64];
    __shared__ float pp[30][8];
    __shared__ float sa[KA_], sbv[KA_], sk[KA_], skst[KA_];
    __shared__ float sphi[U_];
    __shared__ float satt[V_];
    __shared__ int   sseq[U_];
    __shared__ float smask[U_];

    if (bid >= 384){
        // ---------------- window role ----------------
        const int wb = bid - 384;
        if (tid < U_){ sseq[tid] = char_seq[wb*U_+tid]; smask[tid] = char_mask[wb*U_+tid]; }
        __syncthreads();
        for (int t=0; t<T_; ++t){
            BLOCK_WAIT(&c0[t], 128);
            if (tid < 240){
                int r = tid >> 3, p8 = tid & 7;
                const float4* hp = (const float4*)(out0 + (size_t)t*32768);
                const float4* wr = (const float4*)(winW + (size_t)r*H_);
                float acc = 0.f;
                int kq0 = p8*16;
                #pragma unroll 4
                for (int i=0; i<16; ++i){
                    float4 xv = hp[(size_t)(kq0+i)*64 + wb];
                    float4 wv = wr[kq0+i];
                    acc += xv.x*wv.x + xv.y*wv.y + xv.z*wv.z + xv.w*wv.w;
                }
                pp[r][p8] = acc;
            }
            __syncthreads();
            if (tid < 30){
                float p = winb[tid];
                #pragma unroll
                for (int i=0; i<8; ++i) p += pp[tid][i];
                float e = expf(p);
                if (tid < KA_) sa[tid] = e;
                else if (tid < 2*KA_) sbv[tid-KA_] = e;
                else {
                    int a2 = tid - 2*KA_;
                    float kn = ((t == 0) ? 0.f : skst[a2]) + e;
                    skst[a2] = kn; sk[a2] = kn;
                }
            }
            __syncthreads();
            if (tid < U_){
                float acc = 0.f;
                #pragma unroll
                for (int a=0; a<KA_; ++a){
                    float d = sk[a] - (float)tid;
                    acc += sa[a]*expf(-sbv[a]*d*d);
                }
                sphi[tid] = acc * smask[tid]*smask[tid];
            }
            __syncthreads();
            if (tid < V_){
                float wv = 0.f;
                for (int u=0; u<U_; ++u) wv += (sseq[u] == tid) ? sphi[u] : 0.f;
                satt[tid] = wv;
            }
            __syncthreads();
            if (tid < 40){
                unsigned pk = pack_bf16(satt[2*tid], satt[2*tid+1]);
                coh_store_u32(attnb + (size_t)t*2560 + (size_t)wb*40 + tid, pk);
            }
            __syncthreads();           // drain write-through stores (vmcnt)
            if (tid == 0) atomicAdd(&cw[t], 1);
        }
        return;
    }

    // ---------------- layer role ----------------
    const int l  = bid >> 7;          // 0,1,2
    const int ub = (bid & 127) * 4;

    const float* wbase; const float* bias_p; const float* xprev; float* outp;
    int* cself; int* cprev; size_t wstride; int roff;
    if (l == 0){ wbase = wpad;                                          wstride = S0_;  bias_p = b0; outp = out0; xprev = nullptr; cself = c0; cprev = nullptr; roff = 84; }
    else if (l == 1){ wbase = wpad + (size_t)2048*S0_;                  wstride = S12_; bias_p = b1; outp = out1; xprev = out0;   cself = c1; cprev = c0;     roff = 596; }
    else { wbase = wpad + (size_t)2048*S0_ + (size_t)2048*S12_;         wstride = S12_; bias_p = b2; outp = out2; xprev = out1;   cself = c2; cprev = c1;     roff = 596; }

    const float* wr = wbase + ((size_t)g*H_ + ub)*wstride;
    const float* wr1 = wr + wstride;
    const float* wr2 = wr + 2*wstride;
    const float* wr3 = wr + 3*wstride;

    // combine thread (g,b) owns unit u = ub+g
    const int cu = ub + g;
    const float bgi = bias_p[0*H_+cu];
    const float bgf = bias_p[1*H_+cu];
    const float bgg = bias_p[2*H_+cu];
    const float bgo = bias_p[3*H_+cu];
    float creg = 0.f;

    for (int t=0; t<T_; ++t){
        float a0, a1, a2, a3;
        // stroke part (no dependency)
        {
            const float* sr = strokes + ((size_t)b*T_ + t)*3;
            float sx=sr[0], sy=sr[1], sz=sr[2];
            a0 = sx*wr[0]  + sy*wr[1]  + sz*wr[2];
            a1 = sx*wr1[0] + sy*wr1[1] + sz*wr1[2];
            a2 = sx*wr2[0] + sy*wr2[1] + sz*wr2[2];
            a3 = sx*wr3[0] + sy*wr3[1] + sz*wr3[2];
        }
        // own recurrence: needs own layer's h(t-1)
        if (t > 0){
            BLOCK_WAIT(&cself[t-1], 128);
            const float4* hp = (const float4*)(outp + (size_t)(t-1)*32768) + b;
            #pragma unroll 4
            for (int kq=0; kq<128; ++kq){
                float4 xv = hp[kq*64];
                float4 q0 = *(const float4*)(wr  + roff + kq*4);
                float4 q1 = *(const float4*)(wr1 + roff + kq*4);
                float4 q2 = *(const float4*)(wr2 + roff + kq*4);
                float4 q3 = *(const float4*)(wr3 + roff + kq*4);
                a0 += xv.x*q0.x + xv.y*q0.y + xv.z*q0.z + xv.w*q0.w;
                a1 += xv.x*q1.x + xv.y*q1.y + xv.z*q1.z + xv.w*q1.w;
                a2 += xv.x*q2.x + xv.y*q2.y + xv.z*q2.z + xv.w*q2.w;
                a3 += xv.x*q3.x + xv.y*q3.y + xv.z*q3.z + xv.w*q3.w;
            }
        }
        // previous-layer h part (layers 1/2)
        if (l > 0){
            BLOCK_WAIT(&cprev[t], 128);
            const float4* hp = (const float4*)(xprev + (size_t)t*32768) + b;
            #pragma unroll 4
            for (int kq=0; kq<128; ++kq){
                float4 xv = hp[kq*64];
                float4 q0 = *(const float4*)(wr  + 84 + kq*4);
                float4 q1 = *(const float4*)(wr1 + 84 + kq*4);
                float4 q2 = *(const float4*)(wr2 + 84 + kq*4);
                float4 q3 = *(const float4*)(wr3 + 84 + kq*4);
                a0 += xv.x*q0.x + xv.y*q0.y + xv.z*q0.z + xv.w*q0.w;
                a1 += xv.x*q1.x + xv.y*q1.y + xv.z*q1.z + xv.w*q1.w;
                a2 += xv.x*q2.x + xv.y*q2.y + xv.z*q2.z + xv.w*q2.w;
                a3 += xv.x*q3.x + xv.y*q3.y + xv.z*q3.z + xv.w*q3.w;
            }
        }
        // attention part (layer0 uses attn[t-1], layers1/2 attn[t]); bf16 pairs
        {
            int ta = (l == 0) ? (t-1) : t;
            if (ta >= 0){
                BLOCK_WAIT(&cw[ta], 64);
                const uint4* ap = (const uint4*)(attnb + (size_t)ta*2560 + (size_t)b*40);
                #pragma unroll
                for (int j=0; j<10; ++j){
                    uint4 q = ap[j];
                    float x0 = blo(q.x), x1 = bhi(q.x), x2 = blo(q.y), x3 = bhi(q.y);
                    float x4 = blo(q.z), x5 = bhi(q.z), x6 = blo(q.w), x7 = bhi(q.w);
                    float4 qa, qb;
                    qa = *(const float4*)(wr  + 4 + 8*j); qb = *(const float4*)(wr  + 8 + 8*j);
                    a0 += x0*qa.x + x1*qa.y + x2*qa.z + x3*qa.w + x4*qb.x + x5*qb.y + x6*qb.z + x7*qb.w;
                    qa = *(const float4*)(wr1 + 4 + 8*j); qb = *(const float4*)(wr1 + 8 + 8*j);
                    a1 += x0*qa.x + x1*qa.y + x2*qa.z + x3*qa.w + x4*qb.x + x5*qb.y + x6*qb.z + x7*qb.w;
                    qa = *(const float4*)(wr2 + 4 + 8*j); qb = *(const float4*)(wr2 + 8 + 8*j);
                    a2 += x0*qa.x + x1*qa.y + x2*qa.z + x3*qa.w + x4*qb.x + x5*qb.y + x6*qb.z + x7*qb.w;
                    qa = *(const float4*)(wr3 + 4 + 8*j); qb = *(const float4*)(wr3 + 8 + 8*j);
                    a3 += x0*qa.x + x1*qa.y + x2*qa.z + x3*qa.w + x4*qb.x + x5*qb.y + x6*qb.z + x7*qb.w;
                }
            }
        }
        part[g][0][b] = a0;
        part[g][1][b] = a1;
        part[g][2][b] = a2;
        part[g][3][b] = a3;
        __syncthreads();
        {
            // combine: thread (g,b) finishes unit cu = ub+g
            float gi  = part[0][g][b] + bgi;
            float gf  = part[1][g][b] + bgf;
            float gg_ = part[2][g][b] + bgg;
            float go  = part[3][g][b] + bgo;
            float cold = (t == 0) ? 0.f : creg;
            float cnew = sigmf(gf)*cold + sigmf(gi)*tanhf(gg_);
            creg = cnew;
            float h = sigmf(go)*tanhf(cnew);
            coh_store_f32(outp + (size_t)t*32768 + (size_t)(cu>>2)*256 + b*4 + (cu&3), h);
        }
        __syncthreads();               // drain write-through stores (vmcnt)
        if (tid == 0) atomicAdd(&cself[t], 1);
    }
}

// ---------------------------------------------------------------------------
// FC head + output transforms, fused. One block per t. (unchanged; h is fp32)
__global__ __launch_bounds__(256) void k_fc(
    const float* __restrict__ out0, const float* __restrict__ out1, const float* __restrict__ out2,
    const float* __restrict__ fcW, const float* __restrict__ fcb, float* __restrict__ out)
{
    int t = blockIdx.x; int tid = threadIdx.x;
    int b = tid & 63; int gq = tid >> 6;
    __shared__ float smraw[128*65];   // union: acts[128][65] / fin[121][64]

    float acc[31];
    #pragma unroll
    for (int i=0; i<31; ++i) acc[i] = 0.f;

    const float* outs[3] = {out0, out1, out2};
    for (int seg=0; seg<3; ++seg){
        const float* o = outs[seg] + (size_t)t*32768;
        for (int kc=0; kc<H_; kc+=128){
            __syncthreads();
            #pragma unroll
            for (int r=0; r<8; ++r){
                int idx = tid + 256*r;          // 0..2047
                int kql = idx >> 6;             // 0..31
                int bb  = idx & 63;
                float4 v = *(const float4*)(o + (size_t)((kc>>2) + kql)*256 + bb*4);
                smraw[(4*kql+0)*65+bb] = v.x;
                smraw[(4*kql+1)*65+bb] = v.y;
                smraw[(4*kql+2)*65+bb] = v.z;
                smraw[(4*kql+3)*65+bb] = v.w;
            }
            __syncthreads();
            for (int kk=0; kk<128; kk+=4){
                float a0 = smraw[(kk+0)*65+b];
                float a1 = smraw[(kk+1)*65+b];
                float a2 = smraw[(kk+2)*65+b];
                float a3 = smraw[(kk+3)*65+b];
                int K = seg*H_ + kc + kk;
                #pragma unroll
                for (int i=0; i<30; ++i){
                    float4 w = *(const float4*)(fcW + (size_t)(gq+4*i)*1536 + K);
                    acc[i] += a0*w.x + a1*w.y + a2*w.z + a3*w.w;
                }
                if (gq == 0){
                    float4 w = *(const float4*)(fcW + (size_t)120*1536 + K);
                    acc[30] += a0*w.x + a1*w.y + a2*w.z + a3*w.w;
                }
            }
        }
    }
    __syncthreads();
    #pragma unroll
    for (int i=0; i<30; ++i) smraw[(gq+4*i)*64 + b] = acc[i] + fcb[gq+4*i];
    if (gq == 0) smraw[120*64 + b] = acc[30] + fcb[120];
    __syncthreads();

    if (tid < 64){
        size_t bt = (size_t)b*T_ + t;
        float* myu = out + 768000;
        #pragma unroll
        for (int q=0; q<10; ++q){
            float4 v;
            v.x = smraw[(4*q+0)*64+b]; v.y = smraw[(4*q+1)*64+b];
            v.z = smraw[(4*q+2)*64+b]; v.w = smraw[(4*q+3)*64+b];
            *(float4*)(myu + bt*40 + 4*q) = v;
        }
        float* lsg = out + 2304000;
        #pragma unroll
        for (int q=0; q<10; ++q){
            float4 v;
            v.x = smraw[(40+4*q+0)*64+b]; v.y = smraw[(40+4*q+1)*64+b];
            v.z = smraw[(40+4*q+2)*64+b]; v.w = smraw[(40+4*q+3)*64+b];
            *(float4*)(lsg + bt*40 + 4*q) = v;
        }
        float pi[KO_];
        float m = -1e30f;
        #pragma unroll
        for (int ko=0; ko<KO_; ++ko){ pi[ko] = smraw[(80+ko)*64+b]; m = fmaxf(m, pi[ko]); }
        float s = 0.f;
        #pragma unroll
        for (int ko=0; ko<KO_; ++ko) s += expf(pi[ko]-m);
        float lse = m + logf(s);
        #pragma unroll
        for (int q=0; q<5; ++q){
            float4 v;
            v.x = pi[4*q+0]-lse; v.y = pi[4*q+1]-lse; v.z = pi[4*q+2]-lse; v.w = pi[4*q+3]-lse;
            *(float4*)(out + bt*20 + 4*q) = v;
        }
        float* rho = out + 3840000;
        #pragma unroll
        for (int q=0; q<5; ++q){
            float4 v;
            v.x = tanhf(smraw[(100+4*q+0)*64+b]); v.y = tanhf(smraw[(100+4*q+1)*64+b]);
            v.z = tanhf(smraw[(100+4*q+2)*64+b]); v.w = tanhf(smraw[(100+4*q+3)*64+b]);
            *(float4*)(rho + bt*20 + 4*q) = v;
        }
        out[4608000 + bt] = 1.f/(1.f + expf(smraw[120*64+b]));
    }
}

// ---------------------------------------------------------------------------
extern "C" void kernel_launch(void* const* d_in, const int* in_sizes, int n_in,
                              void* d_out, int out_size, void* d_ws, size_t ws_size,
                              hipStream_t stream)
{
    const int*   char_seq  = (const int*)  d_in[0];
    const float* char_mask = (const float*)d_in[1];
    const float* strokes   = (const float*)d_in[2];
    const float* W0ih = (const float*)d_in[4];
    const float* W0hh = (const float*)d_in[5];
    const float* b0   = (const float*)d_in[6];
    const float* winW = (const float*)d_in[7];
    const float* winb = (const float*)d_in[8];
    const float* W1ih = (const float*)d_in[9];
    const float* W1hh = (const float*)d_in[10];
    const float* b1   = (const float*)d_in[11];
    const float* W2ih = (const float*)d_in[12];
    const float* W2hh = (const float*)d_in[13];
    const float* b2   = (const float*)d_in[14];
    const float* fcW  = (const float*)d_in[15];
    const float* fcb  = (const float*)d_in[16];

    float* ws   = (float*)d_ws;
    float*    out0  = ws;                          // [600][128][64][4] = 19,660,800 fl
    float*    out1  = out0 + 19660800;
    float*    out2  = out1 + 19660800;
    unsigned* attnb = (unsigned*)(out2 + 19660800);// bf16 pairs [600][64][40] = 1,536,000 u32
    float*    wpad  = (float*)(attnb + 1536000);   // 5,767,168 fl
    int*      sync  = (int*)(wpad + 5767168);      // 2,560 ints  (total 265,152,512 B)

    hipMemsetAsync(sync, 0, 2560*sizeof(int), stream);

    hipLaunchKernelGGL(k_prep, dim3(6144), dim3(64), 0, stream,
        W0ih, W0hh, W1ih, W1hh, W2ih, W2hh, wpad);

    hipLaunchKernelGGL(k_pipe, dim3(448), dim3(256), 0, stream,
        strokes, char_seq, char_mask, wpad, winW, winb, b0, b1, b2,
        out0, out1, out2, attnb, sync);

    hipLaunchKernelGGL(k_fc, dim3(600), dim3(256), 0, stream,
        out0, out1, out2, fcW, fcb, (float*)d_out);
}